// Round 6
// baseline (268.871 us; speedup 1.0000x reference)
//
#include <hip/hip_runtime.h>

#define SEQ     2048
#define HDIM    1024
#define TOKENS  4096   // B*SEQ
#define NHEADS  16
#define HS      64
#define LP      72     // padded LDS row stride (elements): 144B, 16B-aligned

typedef __bf16 v8bf __attribute__((ext_vector_type(8)));
typedef float  v4f  __attribute__((ext_vector_type(4)));

#define MFMA16(a, b, c) __builtin_amdgcn_mfma_f32_16x16x32_bf16((a), (b), (c), 0, 0, 0)

// scores arrive in log2 units: 1/sqrt(64) * log2(e) folded into Q pre-scale
#define QSCALE (0.125f * 1.44269504088896f)

__device__ __forceinline__ unsigned short f2bf(float f) {
  unsigned int u = __float_as_uint(f);
  u += 0x7FFFu + ((u >> 16) & 1u);   // RNE
  return (unsigned short)(u >> 16);
}
__device__ __forceinline__ float bf2f(unsigned short u) {
  return __uint_as_float((unsigned int)u << 16);
}

__device__ __forceinline__ void async16(const void* g, void* l) {
  __builtin_amdgcn_global_load_lds(
      (const __attribute__((address_space(1))) void*)g,
      (__attribute__((address_space(3))) void*)l, 16, 0, 0);
}

// ---------------- fused prep: x casts + both weight transposes ----------------
__global__ __launch_bounds__(256) void prep_all_kernel(
    const float* __restrict__ x, const float* __restrict__ pos,
    const float* __restrict__ Wqkv, const float* __restrict__ Wout,
    unsigned short* __restrict__ X, unsigned short* __restrict__ XP,
    unsigned short* __restrict__ WQT, unsigned short* __restrict__ WOT) {
  __shared__ float tile[32][33];
  const int id = blockIdx.x;
  if (id < 4096) {
    const int i = (id * 256 + threadIdx.x) * 4;
    float4 xv = *(const float4*)(x + i);
    float4 pv = *(const float4*)(pos + (i & (SEQ * HDIM - 1)));
    ushort4 a, b;
    a.x = f2bf(xv.x); a.y = f2bf(xv.y); a.z = f2bf(xv.z); a.w = f2bf(xv.w);
    b.x = f2bf(xv.x + pv.x); b.y = f2bf(xv.y + pv.y);
    b.z = f2bf(xv.z + pv.z); b.w = f2bf(xv.w + pv.w);
    *(ushort4*)(X + i) = a;
    *(ushort4*)(XP + i) = b;
    return;
  }
  const float* in; unsigned short* out; int R, C, bx, by;
  if (id < 7168) {
    const int t2 = id - 4096;
    in = Wqkv; out = WQT; R = HDIM; C = 3 * HDIM;
    bx = (t2 % 96) * 32; by = (t2 / 96) * 32;
  } else {
    const int t3 = id - 7168;
    in = Wout; out = WOT; R = HDIM; C = HDIM;
    bx = (t3 & 31) * 32; by = (t3 >> 5) * 32;
  }
  const int tx = threadIdx.x & 31, ty = threadIdx.x >> 5;  // (32,8)
#pragma unroll
  for (int j = 0; j < 32; j += 8)
    tile[ty + j][tx] = in[(size_t)(by + ty + j) * C + bx + tx];
  __syncthreads();
#pragma unroll
  for (int j = 0; j < 32; j += 8)
    out[(size_t)(bx + ty + j) * R + by + tx] = f2bf(tile[tx][ty + j]);
}

// ---------------- GEMM1: C(4096x3072) = Aeff(4096x1024) @ Wt(3072x1024)^T ----------------
// Lean: 16KB LDS, no staged epilogue. V packs 4 consecutive-s values per lane
// into one b64 store (contiguous in V^T); Q/K scatter in 32B d-runs.
__global__ __launch_bounds__(256) void gemm_qkv_kernel(
    const unsigned short* __restrict__ XP, const unsigned short* __restrict__ X,
    const unsigned short* __restrict__ Wt,
    unsigned short* __restrict__ Qb, unsigned short* __restrict__ Kb,
    unsigned short* __restrict__ VTb) {
  __shared__ unsigned short As[128 * 32];
  __shared__ unsigned short Bs[128 * 32];
  const int m0 = blockIdx.x * 128;
  const int n0 = blockIdx.y * 128;
  const unsigned short* A = (n0 < 2 * HDIM) ? XP : X;
  const int t = threadIdx.x;
  const int lane = t & 63, w = t >> 6;
  const int wm = (w >> 1) * 64, wn = (w & 1) * 64;
  const int quad = lane >> 4, l15 = lane & 15;

  v4f acc[4][4] = {};

  const int rowA = t >> 2;
  const int colA = (t & 3) * 8;
  const unsigned short* gA = A + (size_t)(m0 + rowA) * HDIM + colA;
  const unsigned short* gB = Wt + (size_t)(n0 + rowA) * HDIM + colA;
  unsigned short* lA = &As[t * 8];
  unsigned short* lB = &Bs[t * 8];

  for (int k0 = 0; k0 < HDIM; k0 += 32) {
    __syncthreads();
    async16(gA + k0, lA);
    async16(gA + 64 * HDIM + k0, lA + 64 * 32);
    async16(gB + k0, lB);
    async16(gB + 64 * HDIM + k0, lB + 64 * 32);
    __syncthreads();
    v8bf a[4], b[4];
#pragma unroll
    for (int i = 0; i < 4; i++)
      a[i] = *(const v8bf*)&As[(wm + i * 16 + l15) * 32 + quad * 8];
#pragma unroll
    for (int i = 0; i < 4; i++)
      b[i] = *(const v8bf*)&Bs[(wn + i * 16 + l15) * 32 + quad * 8];
#pragma unroll
    for (int i = 0; i < 4; i++)
#pragma unroll
      for (int j = 0; j < 4; j++)
        acc[i][j] = MFMA16(a[i], b[j], acc[i][j]);
  }

  const int b_ = m0 >> 11;
  const int s0 = m0 & (SEQ - 1);

  if (n0 >= 2 * HDIM) {
    // V^T[(b,h,d), s]: acc[i][j][0..3] = 4 consecutive s at fixed d -> b64 store
#pragma unroll
    for (int i = 0; i < 4; i++) {
#pragma unroll
      for (int j = 0; j < 4; j++) {
        const int c2 = (n0 - 2 * HDIM) + wn + j * 16 + l15;
        const int h = c2 >> 6, d = c2 & 63;
        const int s_ = s0 + wm + i * 16 + quad * 4;
        ushort4 u;
        u.x = f2bf(acc[i][j][0]); u.y = f2bf(acc[i][j][1]);
        u.z = f2bf(acc[i][j][2]); u.w = f2bf(acc[i][j][3]);
        *(ushort4*)(VTb + ((size_t)(((b_ << 4) | h) * HS + d)) * SEQ + s_) = u;
      }
    }
  } else {
    // Q/K[(b,h,s), d]: scatter, 16 consecutive lanes form 32B d-runs
    const float scale = (n0 < HDIM) ? QSCALE : 1.0f;
    unsigned short* dst = (n0 < HDIM) ? Qb : Kb;
#pragma unroll
    for (int i = 0; i < 4; i++) {
#pragma unroll
      for (int j = 0; j < 4; j++) {
#pragma unroll
        for (int r = 0; r < 4; r++) {
          const int s_ = s0 + wm + i * 16 + quad * 4 + r;
          const int c2 = (n0 & (HDIM - 1)) + wn + j * 16 + l15;
          const int h = c2 >> 6, d = c2 & 63;
          dst[((size_t)(((b_ << 4) | h) * SEQ + s_)) * HS + d] =
              f2bf(acc[i][j][r] * scale);
        }
      }
    }
  }
}

// ---------------- flash attention: complementary pairs x chunk-parity split ----------------
// Block (p, s, bh): q-tiles qlo=p, qhi=31-p (64 rows each); processes key-chunks
// cI ≡ s (mod 2), cI <= qhi. ~16.5 chunk-slots per block, 1024 blocks = 4/CU.
// LDS: Ks+Vs+(Qs|Ps union) = 36,864B. All tiles write 2-segment partials.
__global__ __launch_bounds__(256, 4) void attn_kernel(
    const unsigned short* __restrict__ Qp, const unsigned short* __restrict__ Kp,
    const unsigned short* __restrict__ Vp,
    unsigned short* __restrict__ PART_O, float* __restrict__ PART_L) {
  __shared__ unsigned short SM[18432];     // 36,864 B
  unsigned short* Ks = SM;                 // 64*72
  unsigned short* Vs = SM + 4608;          // 64*72  (V^T chunk: [d][key])
  unsigned short* QPs = SM + 9216;         // 128*72 union: Qs (init) / Ps (loop)

  const int p  = blockIdx.x >> 1;          // 0..15
  const int sg = blockIdx.x & 1;           // chunk parity
  const int bh = blockIdx.y;
  const int qlo = p, qhi = 31 - p;
  const int q0lo = qlo * 64, q0hi = qhi * 64;
  const int t = threadIdx.x;
  const int lane = t & 63, w = t >> 6;
  const int quad = lane >> 4, l15 = lane & 15;

  const unsigned short* Qg = Qp + (size_t)bh * SEQ * HS;
  const unsigned short* Kg = Kp + (size_t)bh * SEQ * HS;
  const unsigned short* Vg = Vp + (size_t)bh * HS * SEQ;

  const int sr = t >> 3, scol = (t & 7) * 8;
  *(uint4*)&QPs[sr * LP + scol] = *(const uint4*)(Qg + (size_t)(q0lo + sr) * HS + scol);
  *(uint4*)&QPs[(sr + 32) * LP + scol] =
      *(const uint4*)(Qg + (size_t)(q0lo + sr + 32) * HS + scol);
  *(uint4*)&QPs[(sr + 64) * LP + scol] =
      *(const uint4*)(Qg + (size_t)(q0hi + sr) * HS + scol);
  *(uint4*)&QPs[(sr + 96) * LP + scol] =
      *(const uint4*)(Qg + (size_t)(q0hi + sr + 32) * HS + scol);
  __syncthreads();

  // Q rows as B-operand fragments: [tile][khalf]; after this QPs becomes Ps
  v8bf bq[2][2];
#pragma unroll
  for (int tl = 0; tl < 2; tl++)
#pragma unroll
    for (int kh = 0; kh < 2; kh++)
      bq[tl][kh] = *(const v8bf*)&QPs[(tl * 64 + w * 16 + l15) * LP + kh * 32 + quad * 8];

  unsigned short* Ps_w = QPs + w * 32 * LP;  // 32 rows/wave: 0-15 lo, 16-31 hi

  v8bf ones;
#pragma unroll
  for (int j = 0; j < 8; j++) ones[j] = (__bf16)1.0f;

  v4f o[2][4] = {};
  v4f lacc[2] = {};

  // register prefetch of first chunk (cI = sg)
  uint4 kr0, kr1, vr0, vr1;
  {
    const int kc = sg * 64;
    kr0 = *(const uint4*)(Kg + (size_t)(kc + sr) * HS + scol);
    kr1 = *(const uint4*)(Kg + (size_t)(kc + sr + 32) * HS + scol);
    vr0 = *(const uint4*)(Vg + (size_t)sr * SEQ + kc + scol);
    vr1 = *(const uint4*)(Vg + (size_t)(sr + 32) * SEQ + kc + scol);
  }

  const int qrow_hi = q0hi + w * 16 + l15;  // lane's q-row in S^T
  const int qrow_lo = q0lo + w * 16 + l15;

  for (int cI = sg; cI <= qhi; cI += 2) {
    const int kc = cI * 64;
    __syncthreads();  // previous chunk's K/V LDS reads done (also covers bq reads)
    *(uint4*)&Ks[sr * LP + scol] = kr0;
    *(uint4*)&Ks[(sr + 32) * LP + scol] = kr1;
    *(uint4*)&Vs[sr * LP + scol] = vr0;
    *(uint4*)&Vs[(sr + 32) * LP + scol] = vr1;
    if (cI + 2 <= qhi) {  // prefetch next parity chunk
      const int kn = kc + 128;
      kr0 = *(const uint4*)(Kg + (size_t)(kn + sr) * HS + scol);
      kr1 = *(const uint4*)(Kg + (size_t)(kn + sr + 32) * HS + scol);
      vr0 = *(const uint4*)(Vg + (size_t)sr * SEQ + kn + scol);
      vr1 = *(const uint4*)(Vg + (size_t)(sr + 32) * SEQ + kn + scol);
    }
    __syncthreads();

    // K fragments (A-operand), shared across both tiles
    v8bf kf0[4], kf1[4];
#pragma unroll
    for (int ni = 0; ni < 4; ni++) {
      kf0[ni] = *(const v8bf*)&Ks[(ni * 16 + l15) * LP + quad * 8];
      kf1[ni] = *(const v8bf*)&Ks[(ni * 16 + l15) * LP + 32 + quad * 8];
    }

    const bool doLo = (cI <= qlo);

    // ---- hi tile: S^T = K Q^T, D[key=quad*4+r][qrow=l15] ----
    {
      v4f sc[4] = {};
#pragma unroll
      for (int ni = 0; ni < 4; ni++) {
        sc[ni] = MFMA16(kf0[ni], bq[1][0], sc[ni]);
        sc[ni] = MFMA16(kf1[ni], bq[1][1], sc[ni]);
      }
      if (cI == qhi) {
#pragma unroll
        for (int ni = 0; ni < 4; ni++) {
          const int key = kc + ni * 16 + quad * 4;
#pragma unroll
          for (int r = 0; r < 4; r++)
            if (key + r > qrow_hi) sc[ni][r] = -1e30f;
        }
      }
#pragma unroll
      for (int ni = 0; ni < 4; ni++) {
        const float p0 = exp2f(sc[ni][0]), p1 = exp2f(sc[ni][1]);
        const float p2 = exp2f(sc[ni][2]), p3 = exp2f(sc[ni][3]);
        uint2 pk;
        pk.x = __builtin_amdgcn_perm(__float_as_uint(p1), __float_as_uint(p0), 0x07060302u);
        pk.y = __builtin_amdgcn_perm(__float_as_uint(p3), __float_as_uint(p2), 0x07060302u);
        *(uint2*)&Ps_w[(16 + l15) * LP + ni * 16 + quad * 4] = pk;
      }
    }
    // ---- lo tile (wave-uniform skip once cI > qlo) ----
    if (doLo) {
      v4f sc[4] = {};
#pragma unroll
      for (int ni = 0; ni < 4; ni++) {
        sc[ni] = MFMA16(kf0[ni], bq[0][0], sc[ni]);
        sc[ni] = MFMA16(kf1[ni], bq[0][1], sc[ni]);
      }
      if (cI == qlo) {
#pragma unroll
        for (int ni = 0; ni < 4; ni++) {
          const int key = kc + ni * 16 + quad * 4;
#pragma unroll
          for (int r = 0; r < 4; r++)
            if (key + r > qrow_lo) sc[ni][r] = -1e30f;
        }
      }
#pragma unroll
      for (int ni = 0; ni < 4; ni++) {
        const float p0 = exp2f(sc[ni][0]), p1 = exp2f(sc[ni][1]);
        const float p2 = exp2f(sc[ni][2]), p3 = exp2f(sc[ni][3]);
        uint2 pk;
        pk.x = __builtin_amdgcn_perm(__float_as_uint(p1), __float_as_uint(p0), 0x07060302u);
        pk.y = __builtin_amdgcn_perm(__float_as_uint(p3), __float_as_uint(p2), 0x07060302u);
        *(uint2*)&Ps_w[l15 * LP + ni * 16 + quad * 4] = pk;
      }
    }

    // ---- O += P @ V, l += P @ 1; V fragments shared across tiles ----
#pragma unroll
    for (int ki = 0; ki < 2; ki++) {
      v8bf pahi = *(const v8bf*)&Ps_w[(16 + l15) * LP + ki * 32 + quad * 8];
      lacc[1] = MFMA16(pahi, ones, lacc[1]);
      v8bf palo;
      if (doLo) {
        palo = *(const v8bf*)&Ps_w[l15 * LP + ki * 32 + quad * 8];
        lacc[0] = MFMA16(palo, ones, lacc[0]);
      }
#pragma unroll
      for (int ni = 0; ni < 4; ni++) {
        v8bf vb = *(const v8bf*)&Vs[(ni * 16 + l15) * LP + ki * 32 + quad * 8];
        o[1][ni] = MFMA16(pahi, vb, o[1][ni]);
        if (doLo) o[0][ni] = MFMA16(palo, vb, o[0][ni]);
      }
    }
  }

  // write unnormalized partials + l for both tiles
#pragma unroll
  for (int tl = 0; tl < 2; tl++) {
    const int slot = (((bh * 16 + p) * 2 + tl) * 2) + sg;
    unsigned short* po = PART_O + (size_t)slot * 4096;
    const int rb = w * 16 + quad * 4;
#pragma unroll
    for (int ni = 0; ni < 4; ni++)
#pragma unroll
      for (int r = 0; r < 4; r++)
        po[(rb + r) * 64 + ni * 16 + l15] = f2bf(o[tl][ni][r]);
    if (l15 == 0) {
      float* pl = PART_L + (size_t)slot * 64;
#pragma unroll
      for (int r = 0; r < 4; r++) pl[rb + r] = lacc[tl][r];
    }
  }
}

// ---------------- combine the 2 parity segments per q-tile ----------------
__global__ __launch_bounds__(256) void combine_kernel(
    const unsigned short* __restrict__ PART_O, const float* __restrict__ PART_L,
    unsigned short* __restrict__ ATTN) {
  const int q = blockIdx.x;                 // 0..31 q-tile
  const int bh = blockIdx.y;
  const int b_ = bh >> 4, h = bh & 15;
  const int p = min(q, 31 - q);
  const int tl = (q >= 16) ? 1 : 0;
  const int base = ((bh * 16 + p) * 2 + tl) * 2;
  const int t = threadIdx.x;
  const int row = t >> 2, c0 = (t & 3) * 16;

  const float Lsum = PART_L[(size_t)base * 64 + row] +
                     PART_L[(size_t)(base + 1) * 64 + row];
  const float inv = 1.0f / Lsum;

  float acc[16];
#pragma unroll
  for (int j = 0; j < 16; j++) acc[j] = 0.0f;
#pragma unroll
  for (int s = 0; s < 2; s++) {
    const unsigned short* po = PART_O + (size_t)(base + s) * 4096 + row * 64 + c0;
    ushort4 u0 = *(const ushort4*)(po);
    ushort4 u1 = *(const ushort4*)(po + 4);
    ushort4 u2 = *(const ushort4*)(po + 8);
    ushort4 u3 = *(const ushort4*)(po + 12);
    acc[0]  += bf2f(u0.x); acc[1]  += bf2f(u0.y);
    acc[2]  += bf2f(u0.z); acc[3]  += bf2f(u0.w);
    acc[4]  += bf2f(u1.x); acc[5]  += bf2f(u1.y);
    acc[6]  += bf2f(u1.z); acc[7]  += bf2f(u1.w);
    acc[8]  += bf2f(u2.x); acc[9]  += bf2f(u2.y);
    acc[10] += bf2f(u2.z); acc[11] += bf2f(u2.w);
    acc[12] += bf2f(u3.x); acc[13] += bf2f(u3.y);
    acc[14] += bf2f(u3.z); acc[15] += bf2f(u3.w);
  }

  const int tr = b_ * SEQ + q * 64 + row;
  unsigned short* dst = ATTN + (size_t)tr * HDIM + h * HS + c0;
  ushort4 o0, o1, o2, o3;
  o0.x = f2bf(acc[0] * inv);  o0.y = f2bf(acc[1] * inv);
  o0.z = f2bf(acc[2] * inv);  o0.w = f2bf(acc[3] * inv);
  o1.x = f2bf(acc[4] * inv);  o1.y = f2bf(acc[5] * inv);
  o1.z = f2bf(acc[6] * inv);  o1.w = f2bf(acc[7] * inv);
  o2.x = f2bf(acc[8] * inv);  o2.y = f2bf(acc[9] * inv);
  o2.z = f2bf(acc[10] * inv); o2.w = f2bf(acc[11] * inv);
  o3.x = f2bf(acc[12] * inv); o3.y = f2bf(acc[13] * inv);
  o3.z = f2bf(acc[14] * inv); o3.w = f2bf(acc[15] * inv);
  *(ushort4*)(dst) = o0;
  *(ushort4*)(dst + 4) = o1;
  *(ushort4*)(dst + 8) = o2;
  *(ushort4*)(dst + 12) = o3;
}

// ---------------- GEMM2: out(4096x1024) = ATTN @ WOT^T, fp32 out ----------------
__global__ __launch_bounds__(256) void gemm_out_kernel(
    const unsigned short* __restrict__ Ab, const unsigned short* __restrict__ Wt,
    float* __restrict__ out) {
  __shared__ unsigned short As[128 * 32];
  __shared__ unsigned short Bs[128 * 32];
  const int m0 = blockIdx.x * 128;
  const int n0 = blockIdx.y * 128;
  const int t = threadIdx.x;
  const int lane = t & 63, w = t >> 6;
  const int wm = (w >> 1) * 64, wn = (w & 1) * 64;
  const int quad = lane >> 4, l15 = lane & 15;

  v4f acc[4][4] = {};

  const int rowA = t >> 2;
  const int colA = (t & 3) * 8;
  const unsigned short* gA = Ab + (size_t)(m0 + rowA) * HDIM + colA;
  const unsigned short* gB = Wt + (size_t)(n0 + rowA) * HDIM + colA;
  unsigned short* lA = &As[t * 8];
  unsigned short* lB = &Bs[t * 8];

  for (int k0 = 0; k0 < HDIM; k0 += 32) {
    __syncthreads();
    async16(gA + k0, lA);
    async16(gA + 64 * HDIM + k0, lA + 64 * 32);
    async16(gB + k0, lB);
    async16(gB + 64 * HDIM + k0, lB + 64 * 32);
    __syncthreads();
    v8bf a[4], b[4];
#pragma unroll
    for (int i = 0; i < 4; i++)
      a[i] = *(const v8bf*)&As[(wm + i * 16 + l15) * 32 + quad * 8];
#pragma unroll
    for (int i = 0; i < 4; i++)
      b[i] = *(const v8bf*)&Bs[(wn + i * 16 + l15) * 32 + quad * 8];
#pragma unroll
    for (int i = 0; i < 4; i++)
#pragma unroll
      for (int j = 0; j < 4; j++)
        acc[i][j] = MFMA16(a[i], b[j], acc[i][j]);
  }

#pragma unroll
  for (int i = 0; i < 4; i++) {
#pragma unroll
    for (int j = 0; j < 4; j++) {
#pragma unroll
      for (int r = 0; r < 4; r++) {
        const int tr = m0 + wm + i * 16 + quad * 4 + r;
        const int c = n0 + wn + j * 16 + l15;
        out[(size_t)tr * HDIM + c] = acc[i][j][r];
      }
    }
  }
}

extern "C" void kernel_launch(void* const* d_in, const int* in_sizes, int n_in,
                              void* d_out, int out_size, void* d_ws, size_t ws_size,
                              hipStream_t stream) {
  (void)in_sizes; (void)n_in; (void)out_size; (void)ws_size;
  const float* x    = (const float*)d_in[0];
  const float* pos  = (const float*)d_in[1];
  const float* Wqkv = (const float*)d_in[2];
  const float* Wout = (const float*)d_in[3];
  float* out = (float*)d_out;

  char* ws = (char*)d_ws;
  // [0,22MB): XP/X/WQT live until gemm_qkv completes; region then reused for
  // attention partials (PART_O 16.8MB @0, PART_L 0.5MB @18MB).
  unsigned short* XP   = (unsigned short*)(ws);
  unsigned short* X    = (unsigned short*)(ws + ((size_t)8  << 20));
  unsigned short* WQT  = (unsigned short*)(ws + ((size_t)16 << 20));
  unsigned short* WOT  = (unsigned short*)(ws + ((size_t)22 << 20));
  unsigned short* Qb   = (unsigned short*)(ws + ((size_t)24 << 20));
  unsigned short* Kb   = (unsigned short*)(ws + ((size_t)32 << 20));
  unsigned short* VTb  = (unsigned short*)(ws + ((size_t)40 << 20));
  unsigned short* ATTN = (unsigned short*)(ws + ((size_t)48 << 20));
  unsigned short* PART_O = (unsigned short*)(ws);
  float*          PART_L = (float*)(ws + ((size_t)18 << 20));

  prep_all_kernel<<<8192, 256, 0, stream>>>(x, pos, Wqkv, Wout, X, XP, WQT, WOT);

  dim3 g1(TOKENS / 128, 3 * HDIM / 128);
  gemm_qkv_kernel<<<g1, 256, 0, stream>>>(XP, X, WQT, Qb, Kb, VTb);

  dim3 g2(32, 2 * NHEADS);
  attn_kernel<<<g2, 256, 0, stream>>>(Qb, Kb, VTb, PART_O, PART_L);

  dim3 gc(32, 2 * NHEADS);
  combine_kernel<<<gc, 256, 0, stream>>>(PART_O, PART_L, ATTN);

  dim3 g3(TOKENS / 128, HDIM / 128);
  gemm_out_kernel<<<g3, 256, 0, stream>>>(ATTN, WOT, out);
}

// Round 7
// 191.407 us; speedup vs baseline: 1.4047x; 1.4047x over previous
//
#include <hip/hip_runtime.h>

#define SEQ     2048
#define HDIM    1024
#define TOKENS  4096   // B*SEQ
#define NHEADS  16
#define HS      64
#define LP      72     // padded LDS row stride (elements): 144B, 16B-aligned

typedef __bf16 v8bf __attribute__((ext_vector_type(8)));
typedef float  v4f  __attribute__((ext_vector_type(4)));

#define MFMA16(a, b, c) __builtin_amdgcn_mfma_f32_16x16x32_bf16((a), (b), (c), 0, 0, 0)

// scores arrive in log2 units: 1/sqrt(64) * log2(e) folded into Q pre-scale
#define QSCALE (0.125f * 1.44269504088896f)

__device__ __forceinline__ unsigned short f2bf(float f) {
  unsigned int u = __float_as_uint(f);
  u += 0x7FFFu + ((u >> 16) & 1u);   // RNE
  return (unsigned short)(u >> 16);
}

__device__ __forceinline__ void async16(const void* g, void* l) {
  __builtin_amdgcn_global_load_lds(
      (const __attribute__((address_space(1))) void*)g,
      (__attribute__((address_space(3))) void*)l, 16, 0, 0);
}

// ---------------- fused prep: x casts + both weight transposes ----------------
__global__ __launch_bounds__(256) void prep_all_kernel(
    const float* __restrict__ x, const float* __restrict__ pos,
    const float* __restrict__ Wqkv, const float* __restrict__ Wout,
    unsigned short* __restrict__ X, unsigned short* __restrict__ XP,
    unsigned short* __restrict__ WQT, unsigned short* __restrict__ WOT) {
  __shared__ float tile[32][33];
  const int id = blockIdx.x;
  if (id < 4096) {
    const int i = (id * 256 + threadIdx.x) * 4;
    float4 xv = *(const float4*)(x + i);
    float4 pv = *(const float4*)(pos + (i & (SEQ * HDIM - 1)));
    ushort4 a, b;
    a.x = f2bf(xv.x); a.y = f2bf(xv.y); a.z = f2bf(xv.z); a.w = f2bf(xv.w);
    b.x = f2bf(xv.x + pv.x); b.y = f2bf(xv.y + pv.y);
    b.z = f2bf(xv.z + pv.z); b.w = f2bf(xv.w + pv.w);
    *(ushort4*)(X + i) = a;
    *(ushort4*)(XP + i) = b;
    return;
  }
  const float* in; unsigned short* out; int R, C, bx, by;
  if (id < 7168) {
    const int t2 = id - 4096;
    in = Wqkv; out = WQT; R = HDIM; C = 3 * HDIM;
    bx = (t2 % 96) * 32; by = (t2 / 96) * 32;
  } else {
    const int t3 = id - 7168;
    in = Wout; out = WOT; R = HDIM; C = HDIM;
    bx = (t3 & 31) * 32; by = (t3 >> 5) * 32;
  }
  const int tx = threadIdx.x & 31, ty = threadIdx.x >> 5;  // (32,8)
#pragma unroll
  for (int j = 0; j < 32; j += 8)
    tile[ty + j][tx] = in[(size_t)(by + ty + j) * C + bx + tx];
  __syncthreads();
#pragma unroll
  for (int j = 0; j < 32; j += 8)
    out[(size_t)(bx + ty + j) * R + by + tx] = f2bf(tile[tx][ty + j]);
}

// ---------------- GEMM1: C(4096x3072) = Aeff(4096x1024) @ Wt(3072x1024)^T ----------------
// Lean 16KB LDS. V blocks compute C^T via operand swap so the V^T store is
// 32B s-runs; Q/K scatter in 32B d-runs.
__global__ __launch_bounds__(256) void gemm_qkv_kernel(
    const unsigned short* __restrict__ XP, const unsigned short* __restrict__ X,
    const unsigned short* __restrict__ Wt,
    unsigned short* __restrict__ Qb, unsigned short* __restrict__ Kb,
    unsigned short* __restrict__ VTb) {
  __shared__ unsigned short As[128 * 32];
  __shared__ unsigned short Bs[128 * 32];
  const int m0 = blockIdx.x * 128;
  const int n0 = blockIdx.y * 128;
  const bool isV = (n0 >= 2 * HDIM);
  const unsigned short* A = isV ? X : XP;
  const int t = threadIdx.x;
  const int lane = t & 63, w = t >> 6;
  const int wm = (w >> 1) * 64, wn = (w & 1) * 64;
  const int quad = lane >> 4, l15 = lane & 15;

  v4f acc[4][4] = {};

  const int rowA = t >> 2;
  const int colA = (t & 3) * 8;
  const unsigned short* gA = A + (size_t)(m0 + rowA) * HDIM + colA;
  const unsigned short* gB = Wt + (size_t)(n0 + rowA) * HDIM + colA;
  unsigned short* lA = &As[t * 8];
  unsigned short* lB = &Bs[t * 8];

  for (int k0 = 0; k0 < HDIM; k0 += 32) {
    __syncthreads();
    async16(gA + k0, lA);
    async16(gA + 64 * HDIM + k0, lA + 64 * 32);
    async16(gB + k0, lB);
    async16(gB + 64 * HDIM + k0, lB + 64 * 32);
    __syncthreads();
    v8bf a[4], b[4];
#pragma unroll
    for (int i = 0; i < 4; i++)
      a[i] = *(const v8bf*)&As[(wm + i * 16 + l15) * 32 + quad * 8];
#pragma unroll
    for (int i = 0; i < 4; i++)
      b[i] = *(const v8bf*)&Bs[(wn + i * 16 + l15) * 32 + quad * 8];
    if (isV) {
#pragma unroll
      for (int i = 0; i < 4; i++)
#pragma unroll
        for (int j = 0; j < 4; j++)
          acc[i][j] = MFMA16(b[j], a[i], acc[i][j]);   // C^T
    } else {
#pragma unroll
      for (int i = 0; i < 4; i++)
#pragma unroll
        for (int j = 0; j < 4; j++)
          acc[i][j] = MFMA16(a[i], b[j], acc[i][j]);
    }
  }

  const int b_ = m0 >> 11;
  const int s0 = m0 & (SEQ - 1);

  if (isV) {
    // acc[i][j] = C^T: D[row=quad*4+r -> Wt col (d)][col=l15 -> token (s)]
#pragma unroll
    for (int i = 0; i < 4; i++) {
#pragma unroll
      for (int j = 0; j < 4; j++) {
        const int s_ = s0 + wm + i * 16 + l15;
#pragma unroll
        for (int r = 0; r < 4; r++) {
          const int c2 = (n0 - 2 * HDIM) + wn + j * 16 + quad * 4 + r;
          const int h = c2 >> 6, d = c2 & 63;
          VTb[((size_t)(((b_ << 4) | h) * HS + d)) * SEQ + s_] = f2bf(acc[i][j][r]);
        }
      }
    }
  } else {
    // Q/K[(b,h,s), d]: scatter, 16 consecutive lanes form 32B d-runs
    const float scale = (n0 < HDIM) ? QSCALE : 1.0f;
    unsigned short* dst = (n0 < HDIM) ? Qb : Kb;
#pragma unroll
    for (int i = 0; i < 4; i++) {
#pragma unroll
      for (int j = 0; j < 4; j++) {
#pragma unroll
        for (int r = 0; r < 4; r++) {
          const int s_ = s0 + wm + i * 16 + quad * 4 + r;
          const int c2 = (n0 & (HDIM - 1)) + wn + j * 16 + l15;
          const int h = c2 >> 6, d = c2 & 63;
          dst[((size_t)(((b_ << 4) | h) * SEQ + s_)) * HS + d] =
              f2bf(acc[i][j][r] * scale);
        }
      }
    }
  }
}

// ---------------- flash attention, complementary-pair balanced (R5 structure) ---------
// Block (bh, p) handles q-tiles qlo=p and qhi=31-p (64 rows each), sharing one
// K/V stream over chunks 0..qhi. Every block: exactly 33 chunk-tiles of work.
// blockIdx.x = bh so one bh's 16 blocks land on one XCD (L2 locality).
__global__ __launch_bounds__(256, 2) void attn_pair_kernel(
    const unsigned short* __restrict__ Qp, const unsigned short* __restrict__ Kp,
    const unsigned short* __restrict__ Vp, unsigned short* __restrict__ ATTN) {
  __shared__ unsigned short Qs[128 * LP];    // rows 0-63: lo tile, 64-127: hi tile
  __shared__ unsigned short Ks[64 * LP];
  __shared__ unsigned short Vs[64 * LP];     // V^T chunk: [d][key]
  __shared__ unsigned short Ps[4][32 * LP];  // per-wave P: rows 0-15 lo, 16-31 hi

  const int bh = blockIdx.x;
  const int p  = blockIdx.y;        // 0..15
  const int b_ = bh >> 4, h = bh & 15;
  const int qlo = p, qhi = 31 - p;
  const int q0lo = qlo * 64, q0hi = qhi * 64;
  const int t = threadIdx.x;
  const int lane = t & 63, w = t >> 6;
  const int quad = lane >> 4, l15 = lane & 15;

  const unsigned short* Qg = Qp + (size_t)bh * SEQ * HS;
  const unsigned short* Kg = Kp + (size_t)bh * SEQ * HS;
  const unsigned short* Vg = Vp + (size_t)bh * HS * SEQ;

  const int sr = t >> 3, scol = (t & 7) * 8;
  *(uint4*)&Qs[sr * LP + scol] = *(const uint4*)(Qg + (size_t)(q0lo + sr) * HS + scol);
  *(uint4*)&Qs[(sr + 32) * LP + scol] =
      *(const uint4*)(Qg + (size_t)(q0lo + sr + 32) * HS + scol);
  *(uint4*)&Qs[(sr + 64) * LP + scol] =
      *(const uint4*)(Qg + (size_t)(q0hi + sr) * HS + scol);
  *(uint4*)&Qs[(sr + 96) * LP + scol] =
      *(const uint4*)(Qg + (size_t)(q0hi + sr + 32) * HS + scol);
  __syncthreads();

  // Q rows as B-operand fragments: [tile][khalf]
  v8bf bq[2][2];
#pragma unroll
  for (int tl = 0; tl < 2; tl++)
#pragma unroll
    for (int kh = 0; kh < 2; kh++)
      bq[tl][kh] = *(const v8bf*)&Qs[(tl * 64 + w * 16 + l15) * LP + kh * 32 + quad * 8];

  v8bf ones;
#pragma unroll
  for (int j = 0; j < 8; j++) ones[j] = (__bf16)1.0f;

  v4f o[2][4] = {};
  v4f lacc[2] = {};

  // register prefetch of chunk 0
  uint4 kr0, kr1, vr0, vr1;
  kr0 = *(const uint4*)(Kg + (size_t)sr * HS + scol);
  kr1 = *(const uint4*)(Kg + (size_t)(sr + 32) * HS + scol);
  vr0 = *(const uint4*)(Vg + (size_t)sr * SEQ + scol);
  vr1 = *(const uint4*)(Vg + (size_t)(sr + 32) * SEQ + scol);

  const int qrow_hi = q0hi + w * 16 + l15;  // lane's q-row in S^T
  const int qrow_lo = q0lo + w * 16 + l15;

  for (int cI = 0; cI <= qhi; cI++) {
    const int kc = cI * 64;
    __syncthreads();  // previous chunk's K/V LDS reads done
    *(uint4*)&Ks[sr * LP + scol] = kr0;
    *(uint4*)&Ks[(sr + 32) * LP + scol] = kr1;
    *(uint4*)&Vs[sr * LP + scol] = vr0;
    *(uint4*)&Vs[(sr + 32) * LP + scol] = vr1;
    if (cI < qhi) {  // prefetch next chunk while computing this one
      const int kn = kc + 64;
      kr0 = *(const uint4*)(Kg + (size_t)(kn + sr) * HS + scol);
      kr1 = *(const uint4*)(Kg + (size_t)(kn + sr + 32) * HS + scol);
      vr0 = *(const uint4*)(Vg + (size_t)sr * SEQ + kn + scol);
      vr1 = *(const uint4*)(Vg + (size_t)(sr + 32) * SEQ + kn + scol);
    }
    __syncthreads();

    // K fragments (A-operand), shared across both tiles
    v8bf kf0[4], kf1[4];
#pragma unroll
    for (int ni = 0; ni < 4; ni++) {
      kf0[ni] = *(const v8bf*)&Ks[(ni * 16 + l15) * LP + quad * 8];
      kf1[ni] = *(const v8bf*)&Ks[(ni * 16 + l15) * LP + 32 + quad * 8];
    }

    const bool doLo = (cI <= qlo);

    // ---- hi tile: S^T = K Q^T, D[key=quad*4+r][qrow=l15] ----
    {
      v4f sc[4] = {};
#pragma unroll
      for (int ni = 0; ni < 4; ni++) {
        sc[ni] = MFMA16(kf0[ni], bq[1][0], sc[ni]);
        sc[ni] = MFMA16(kf1[ni], bq[1][1], sc[ni]);
      }
      if (cI == qhi) {
#pragma unroll
        for (int ni = 0; ni < 4; ni++) {
          const int key = kc + ni * 16 + quad * 4;
#pragma unroll
          for (int r = 0; r < 4; r++)
            if (key + r > qrow_hi) sc[ni][r] = -1e30f;
        }
      }
#pragma unroll
      for (int ni = 0; ni < 4; ni++) {
        const float p0 = exp2f(sc[ni][0]), p1 = exp2f(sc[ni][1]);
        const float p2 = exp2f(sc[ni][2]), p3 = exp2f(sc[ni][3]);
        uint2 pk;
        pk.x = __builtin_amdgcn_perm(__float_as_uint(p1), __float_as_uint(p0), 0x07060302u);
        pk.y = __builtin_amdgcn_perm(__float_as_uint(p3), __float_as_uint(p2), 0x07060302u);
        *(uint2*)&Ps[w][(16 + l15) * LP + ni * 16 + quad * 4] = pk;
      }
    }
    // ---- lo tile (wave-uniform skip once cI > qlo) ----
    if (doLo) {
      v4f sc[4] = {};
#pragma unroll
      for (int ni = 0; ni < 4; ni++) {
        sc[ni] = MFMA16(kf0[ni], bq[0][0], sc[ni]);
        sc[ni] = MFMA16(kf1[ni], bq[0][1], sc[ni]);
      }
      if (cI == qlo) {
#pragma unroll
        for (int ni = 0; ni < 4; ni++) {
          const int key = kc + ni * 16 + quad * 4;
#pragma unroll
          for (int r = 0; r < 4; r++)
            if (key + r > qrow_lo) sc[ni][r] = -1e30f;
        }
      }
#pragma unroll
      for (int ni = 0; ni < 4; ni++) {
        const float p0 = exp2f(sc[ni][0]), p1 = exp2f(sc[ni][1]);
        const float p2 = exp2f(sc[ni][2]), p3 = exp2f(sc[ni][3]);
        uint2 pk;
        pk.x = __builtin_amdgcn_perm(__float_as_uint(p1), __float_as_uint(p0), 0x07060302u);
        pk.y = __builtin_amdgcn_perm(__float_as_uint(p3), __float_as_uint(p2), 0x07060302u);
        *(uint2*)&Ps[w][l15 * LP + ni * 16 + quad * 4] = pk;
      }
    }

    // ---- O += P @ V, l += P @ 1; V fragments shared across tiles ----
#pragma unroll
    for (int ki = 0; ki < 2; ki++) {
      v8bf pahi = *(const v8bf*)&Ps[w][(16 + l15) * LP + ki * 32 + quad * 8];
      lacc[1] = MFMA16(pahi, ones, lacc[1]);
      v8bf palo;
      if (doLo) {
        palo = *(const v8bf*)&Ps[w][l15 * LP + ki * 32 + quad * 8];
        lacc[0] = MFMA16(palo, ones, lacc[0]);
      }
#pragma unroll
      for (int ni = 0; ni < 4; ni++) {
        v8bf vb = *(const v8bf*)&Vs[(ni * 16 + l15) * LP + ki * 32 + quad * 8];
        o[1][ni] = MFMA16(pahi, vb, o[1][ni]);
        if (doLo) o[0][ni] = MFMA16(palo, vb, o[0][ni]);
      }
    }
  }

  // epilogue: normalize and store both tiles (C-layout rows = quad*4+r)
#pragma unroll
  for (int tl = 0; tl < 2; tl++) {
    const int q0 = tl ? q0hi : q0lo;
    const int row_base = q0 + w * 16 + quad * 4;
    float invl[4];
#pragma unroll
    for (int r = 0; r < 4; r++) invl[r] = 1.0f / lacc[tl][r];
#pragma unroll
    for (int ni = 0; ni < 4; ni++)
#pragma unroll
      for (int r = 0; r < 4; r++) {
        const int tr = b_ * SEQ + row_base + r;
        ATTN[(size_t)tr * HDIM + h * HS + ni * 16 + l15] = f2bf(o[tl][ni][r] * invl[r]);
      }
  }
}

// ---------------- GEMM2: out(4096x1024) = ATTN @ WOT^T, fp32 out ----------------
// 128x64 tiles -> 512 blocks (2/CU) for latency hiding.
__global__ __launch_bounds__(256) void gemm_out_kernel(
    const unsigned short* __restrict__ Ab, const unsigned short* __restrict__ Wt,
    float* __restrict__ out) {
  __shared__ unsigned short As[128 * 32];
  __shared__ unsigned short Bs[64 * 32];
  const int m0 = blockIdx.x * 128;
  const int n0 = blockIdx.y * 64;
  const int t = threadIdx.x;
  const int lane = t & 63, w = t >> 6;
  const int wm = w * 32;
  const int quad = lane >> 4, l15 = lane & 15;

  v4f acc[2][4] = {};

  const int rowA = t >> 2;
  const int colA = (t & 3) * 8;
  const unsigned short* gA = Ab + (size_t)(m0 + rowA) * HDIM + colA;
  const unsigned short* gB = Wt + (size_t)(n0 + rowA) * HDIM + colA;
  unsigned short* lA = &As[t * 8];
  unsigned short* lB = &Bs[t * 8];   // only first 64 rows' worth used

  for (int k0 = 0; k0 < HDIM; k0 += 32) {
    __syncthreads();
    async16(gA + k0, lA);
    async16(gA + 64 * HDIM + k0, lA + 64 * 32);
    if (rowA < 64) async16(gB + k0, lB);
    __syncthreads();
    v8bf a[2], b[4];
#pragma unroll
    for (int i = 0; i < 2; i++)
      a[i] = *(const v8bf*)&As[(wm + i * 16 + l15) * 32 + quad * 8];
#pragma unroll
    for (int j = 0; j < 4; j++)
      b[j] = *(const v8bf*)&Bs[(j * 16 + l15) * 32 + quad * 8];
#pragma unroll
    for (int i = 0; i < 2; i++)
#pragma unroll
      for (int j = 0; j < 4; j++)
        acc[i][j] = MFMA16(a[i], b[j], acc[i][j]);
  }

#pragma unroll
  for (int i = 0; i < 2; i++) {
#pragma unroll
    for (int j = 0; j < 4; j++) {
#pragma unroll
      for (int r = 0; r < 4; r++) {
        const int tr = m0 + wm + i * 16 + quad * 4 + r;
        const int c = n0 + j * 16 + l15;
        out[(size_t)tr * HDIM + c] = acc[i][j][r];
      }
    }
  }
}

extern "C" void kernel_launch(void* const* d_in, const int* in_sizes, int n_in,
                              void* d_out, int out_size, void* d_ws, size_t ws_size,
                              hipStream_t stream) {
  (void)in_sizes; (void)n_in; (void)out_size; (void)ws_size;
  const float* x    = (const float*)d_in[0];
  const float* pos  = (const float*)d_in[1];
  const float* Wqkv = (const float*)d_in[2];
  const float* Wout = (const float*)d_in[3];
  float* out = (float*)d_out;

  char* ws = (char*)d_ws;
  unsigned short* XP   = (unsigned short*)(ws);
  unsigned short* X    = (unsigned short*)(ws + ((size_t)8  << 20));
  unsigned short* WQT  = (unsigned short*)(ws + ((size_t)16 << 20));
  unsigned short* WOT  = (unsigned short*)(ws + ((size_t)22 << 20));
  unsigned short* Qb   = (unsigned short*)(ws + ((size_t)24 << 20));
  unsigned short* Kb   = (unsigned short*)(ws + ((size_t)32 << 20));
  unsigned short* VTb  = (unsigned short*)(ws + ((size_t)40 << 20));
  unsigned short* ATTN = (unsigned short*)(ws + ((size_t)48 << 20));

  prep_all_kernel<<<8192, 256, 0, stream>>>(x, pos, Wqkv, Wout, X, XP, WQT, WOT);

  dim3 g1(TOKENS / 128, 3 * HDIM / 128);
  gemm_qkv_kernel<<<g1, 256, 0, stream>>>(XP, X, WQT, Qb, Kb, VTb);

  dim3 g2(2 * NHEADS, 16);
  attn_pair_kernel<<<g2, 256, 0, stream>>>(Qb, Kb, VTb, ATTN);

  dim3 g3(TOKENS / 128, HDIM / 64);
  gemm_out_kernel<<<g3, 256, 0, stream>>>(ATTN, WOT, out);
}

// Round 9
// 188.543 us; speedup vs baseline: 1.4260x; 1.0152x over previous
//
#include <hip/hip_runtime.h>

#define SEQ     2048
#define HDIM    1024
#define TOKENS  4096   // B*SEQ
#define NHEADS  16
#define HS      64
#define LP      72     // padded LDS row stride (elements): 144B, 16B-aligned

typedef __bf16 v8bf __attribute__((ext_vector_type(8)));
typedef float  v4f  __attribute__((ext_vector_type(4)));

#define MFMA16(a, b, c) __builtin_amdgcn_mfma_f32_16x16x32_bf16((a), (b), (c), 0, 0, 0)

// scores arrive in log2 units: 1/sqrt(64) * log2(e) folded into Q pre-scale
#define QSCALE (0.125f * 1.44269504088896f)

__device__ __forceinline__ unsigned short f2bf(float f) {
  unsigned int u = __float_as_uint(f);
  u += 0x7FFFu + ((u >> 16) & 1u);   // RNE
  return (unsigned short)(u >> 16);
}

__device__ __forceinline__ void async16(const void* g, void* l) {
  __builtin_amdgcn_global_load_lds(
      (const __attribute__((address_space(1))) void*)g,
      (__attribute__((address_space(3))) void*)l, 16, 0, 0);
}

// ---------------- fused prep: x casts + both weight transposes ----------------
__global__ __launch_bounds__(256) void prep_all_kernel(
    const float* __restrict__ x, const float* __restrict__ pos,
    const float* __restrict__ Wqkv, const float* __restrict__ Wout,
    unsigned short* __restrict__ X, unsigned short* __restrict__ XP,
    unsigned short* __restrict__ WQT, unsigned short* __restrict__ WOT) {
  __shared__ float tile[32][33];
  const int id = blockIdx.x;
  if (id < 4096) {
    const int i = (id * 256 + threadIdx.x) * 4;
    float4 xv = *(const float4*)(x + i);
    float4 pv = *(const float4*)(pos + (i & (SEQ * HDIM - 1)));
    ushort4 a, b;
    a.x = f2bf(xv.x); a.y = f2bf(xv.y); a.z = f2bf(xv.z); a.w = f2bf(xv.w);
    b.x = f2bf(xv.x + pv.x); b.y = f2bf(xv.y + pv.y);
    b.z = f2bf(xv.z + pv.z); b.w = f2bf(xv.w + pv.w);
    *(ushort4*)(X + i) = a;
    *(ushort4*)(XP + i) = b;
    return;
  }
  const float* in; unsigned short* out; int R, C, bx, by;
  if (id < 7168) {
    const int t2 = id - 4096;
    in = Wqkv; out = WQT; R = HDIM; C = 3 * HDIM;
    bx = (t2 % 96) * 32; by = (t2 / 96) * 32;
  } else {
    const int t3 = id - 7168;
    in = Wout; out = WOT; R = HDIM; C = HDIM;
    bx = (t3 & 31) * 32; by = (t3 >> 5) * 32;
  }
  const int tx = threadIdx.x & 31, ty = threadIdx.x >> 5;  // (32,8)
#pragma unroll
  for (int j = 0; j < 32; j += 8)
    tile[ty + j][tx] = in[(size_t)(by + ty + j) * C + bx + tx];
  __syncthreads();
#pragma unroll
  for (int j = 0; j < 32; j += 8)
    out[(size_t)(bx + ty + j) * R + by + tx] = f2bf(tile[tx][ty + j]);
}

// ---------------- GEMM1: C(4096x3072) = Aeff(4096x1024) @ Wt(3072x1024)^T ----------------
// BK=64 (two 32-wide LDS sub-buffers per iter): halves barrier count vs BK=32.
// V blocks compute C^T via operand swap so the V^T store is 32B s-runs.
__global__ __launch_bounds__(256) void gemm_qkv_kernel(
    const unsigned short* __restrict__ XP, const unsigned short* __restrict__ X,
    const unsigned short* __restrict__ Wt,
    unsigned short* __restrict__ Qb, unsigned short* __restrict__ Kb,
    unsigned short* __restrict__ VTb) {
  __shared__ unsigned short As[2][128 * 32];
  __shared__ unsigned short Bs[2][128 * 32];
  const int m0 = blockIdx.x * 128;
  const int n0 = blockIdx.y * 128;
  const bool isV = (n0 >= 2 * HDIM);
  const unsigned short* A = isV ? X : XP;
  const int t = threadIdx.x;
  const int lane = t & 63, w = t >> 6;
  const int wm = (w >> 1) * 64, wn = (w & 1) * 64;
  const int quad = lane >> 4, l15 = lane & 15;

  v4f acc[4][4] = {};

  const int rowA = t >> 2;          // 0..63
  const int colA = (t & 3) * 8;
  const unsigned short* gA = A + (size_t)(m0 + rowA) * HDIM + colA;
  const unsigned short* gB = Wt + (size_t)(n0 + rowA) * HDIM + colA;

  for (int k0 = 0; k0 < HDIM; k0 += 64) {
    __syncthreads();
#pragma unroll
    for (int kh = 0; kh < 2; kh++) {
      async16(gA + k0 + kh * 32, &As[kh][t * 8]);
      async16(gA + 64 * HDIM + k0 + kh * 32, &As[kh][2048 + t * 8]);
      async16(gB + k0 + kh * 32, &Bs[kh][t * 8]);
      async16(gB + 64 * HDIM + k0 + kh * 32, &Bs[kh][2048 + t * 8]);
    }
    __syncthreads();
#pragma unroll
    for (int kh = 0; kh < 2; kh++) {
      v8bf a[4], b[4];
#pragma unroll
      for (int i = 0; i < 4; i++)
        a[i] = *(const v8bf*)&As[kh][(wm + i * 16 + l15) * 32 + quad * 8];
#pragma unroll
      for (int i = 0; i < 4; i++)
        b[i] = *(const v8bf*)&Bs[kh][(wn + i * 16 + l15) * 32 + quad * 8];
      if (isV) {
#pragma unroll
        for (int i = 0; i < 4; i++)
#pragma unroll
          for (int j = 0; j < 4; j++)
            acc[i][j] = MFMA16(b[j], a[i], acc[i][j]);   // C^T
      } else {
#pragma unroll
        for (int i = 0; i < 4; i++)
#pragma unroll
          for (int j = 0; j < 4; j++)
            acc[i][j] = MFMA16(a[i], b[j], acc[i][j]);
      }
    }
  }

  const int b_ = m0 >> 11;
  const int s0 = m0 & (SEQ - 1);

  if (isV) {
    // acc[i][j] = C^T: D[row=quad*4+r -> Wt col (d)][col=l15 -> token (s)]
#pragma unroll
    for (int i = 0; i < 4; i++) {
#pragma unroll
      for (int j = 0; j < 4; j++) {
        const int s_ = s0 + wm + i * 16 + l15;
#pragma unroll
        for (int r = 0; r < 4; r++) {
          const int c2 = (n0 - 2 * HDIM) + wn + j * 16 + quad * 4 + r;
          const int h = c2 >> 6, d = c2 & 63;
          VTb[((size_t)(((b_ << 4) | h) * HS + d)) * SEQ + s_] = f2bf(acc[i][j][r]);
        }
      }
    }
  } else {
    // Q/K[(b,h,s), d]: scatter, 16 consecutive lanes form 32B d-runs
    const float scale = (n0 < HDIM) ? QSCALE : 1.0f;
    unsigned short* dst = (n0 < HDIM) ? Qb : Kb;
#pragma unroll
    for (int i = 0; i < 4; i++) {
#pragma unroll
      for (int j = 0; j < 4; j++) {
#pragma unroll
        for (int r = 0; r < 4; r++) {
          const int s_ = s0 + wm + i * 16 + quad * 4 + r;
          const int c2 = (n0 & (HDIM - 1)) + wn + j * 16 + l15;
          const int h = c2 >> 6, d = c2 & 63;
          dst[((size_t)(((b_ << 4) | h) * SEQ + s_)) * HS + d] =
              f2bf(acc[i][j][r] * scale);
        }
      }
    }
  }
}

// ---------------- flash attention, complementary-pair balanced (R7, verified) ---------
__global__ __launch_bounds__(256, 2) void attn_pair_kernel(
    const unsigned short* __restrict__ Qp, const unsigned short* __restrict__ Kp,
    const unsigned short* __restrict__ Vp, unsigned short* __restrict__ ATTN) {
  __shared__ unsigned short Qs[128 * LP];    // rows 0-63: lo tile, 64-127: hi tile
  __shared__ unsigned short Ks[64 * LP];
  __shared__ unsigned short Vs[64 * LP];     // V^T chunk: [d][key]
  __shared__ unsigned short Ps[4][32 * LP];  // per-wave P: rows 0-15 lo, 16-31 hi

  const int bh = blockIdx.x;
  const int p  = blockIdx.y;        // 0..15
  const int b_ = bh >> 4, h = bh & 15;
  const int qlo = p, qhi = 31 - p;
  const int q0lo = qlo * 64, q0hi = qhi * 64;
  const int t = threadIdx.x;
  const int lane = t & 63, w = t >> 6;
  const int quad = lane >> 4, l15 = lane & 15;

  const unsigned short* Qg = Qp + (size_t)bh * SEQ * HS;
  const unsigned short* Kg = Kp + (size_t)bh * SEQ * HS;
  const unsigned short* Vg = Vp + (size_t)bh * HS * SEQ;

  const int sr = t >> 3, scol = (t & 7) * 8;
  *(uint4*)&Qs[sr * LP + scol] = *(const uint4*)(Qg + (size_t)(q0lo + sr) * HS + scol);
  *(uint4*)&Qs[(sr + 32) * LP + scol] =
      *(const uint4*)(Qg + (size_t)(q0lo + sr + 32) * HS + scol);
  *(uint4*)&Qs[(sr + 64) * LP + scol] =
      *(const uint4*)(Qg + (size_t)(q0hi + sr) * HS + scol);
  *(uint4*)&Qs[(sr + 96) * LP + scol] =
      *(const uint4*)(Qg + (size_t)(q0hi + sr + 32) * HS + scol);
  __syncthreads();

  // Q rows as B-operand fragments: [tile][khalf]
  v8bf bq[2][2];
#pragma unroll
  for (int tl = 0; tl < 2; tl++)
#pragma unroll
    for (int kh = 0; kh < 2; kh++)
      bq[tl][kh] = *(const v8bf*)&Qs[(tl * 64 + w * 16 + l15) * LP + kh * 32 + quad * 8];

  v8bf ones;
#pragma unroll
  for (int j = 0; j < 8; j++) ones[j] = (__bf16)1.0f;

  v4f o[2][4] = {};
  v4f lacc[2] = {};

  // register prefetch of chunk 0
  uint4 kr0, kr1, vr0, vr1;
  kr0 = *(const uint4*)(Kg + (size_t)sr * HS + scol);
  kr1 = *(const uint4*)(Kg + (size_t)(sr + 32) * HS + scol);
  vr0 = *(const uint4*)(Vg + (size_t)sr * SEQ + scol);
  vr1 = *(const uint4*)(Vg + (size_t)(sr + 32) * SEQ + scol);

  const int qrow_hi = q0hi + w * 16 + l15;  // lane's q-row in S^T
  const int qrow_lo = q0lo + w * 16 + l15;

  for (int cI = 0; cI <= qhi; cI++) {
    const int kc = cI * 64;
    __syncthreads();  // previous chunk's K/V LDS reads done
    *(uint4*)&Ks[sr * LP + scol] = kr0;
    *(uint4*)&Ks[(sr + 32) * LP + scol] = kr1;
    *(uint4*)&Vs[sr * LP + scol] = vr0;
    *(uint4*)&Vs[(sr + 32) * LP + scol] = vr1;
    if (cI < qhi) {  // prefetch next chunk while computing this one
      const int kn = kc + 64;
      kr0 = *(const uint4*)(Kg + (size_t)(kn + sr) * HS + scol);
      kr1 = *(const uint4*)(Kg + (size_t)(kn + sr + 32) * HS + scol);
      vr0 = *(const uint4*)(Vg + (size_t)sr * SEQ + kn + scol);
      vr1 = *(const uint4*)(Vg + (size_t)(sr + 32) * SEQ + kn + scol);
    }
    __syncthreads();

    // K fragments (A-operand), shared across both tiles
    v8bf kf0[4], kf1[4];
#pragma unroll
    for (int ni = 0; ni < 4; ni++) {
      kf0[ni] = *(const v8bf*)&Ks[(ni * 16 + l15) * LP + quad * 8];
      kf1[ni] = *(const v8bf*)&Ks[(ni * 16 + l15) * LP + 32 + quad * 8];
    }

    const bool doLo = (cI <= qlo);

    // ---- hi tile: S^T = K Q^T, D[key=quad*4+r][qrow=l15] ----
    {
      v4f sc[4] = {};
#pragma unroll
      for (int ni = 0; ni < 4; ni++) {
        sc[ni] = MFMA16(kf0[ni], bq[1][0], sc[ni]);
        sc[ni] = MFMA16(kf1[ni], bq[1][1], sc[ni]);
      }
      if (cI == qhi) {
#pragma unroll
        for (int ni = 0; ni < 4; ni++) {
          const int key = kc + ni * 16 + quad * 4;
#pragma unroll
          for (int r = 0; r < 4; r++)
            if (key + r > qrow_hi) sc[ni][r] = -1e30f;
        }
      }
#pragma unroll
      for (int ni = 0; ni < 4; ni++) {
        const float p0 = exp2f(sc[ni][0]), p1 = exp2f(sc[ni][1]);
        const float p2 = exp2f(sc[ni][2]), p3 = exp2f(sc[ni][3]);
        uint2 pk;
        pk.x = __builtin_amdgcn_perm(__float_as_uint(p1), __float_as_uint(p0), 0x07060302u);
        pk.y = __builtin_amdgcn_perm(__float_as_uint(p3), __float_as_uint(p2), 0x07060302u);
        *(uint2*)&Ps[w][(16 + l15) * LP + ni * 16 + quad * 4] = pk;
      }
    }
    // ---- lo tile (wave-uniform skip once cI > qlo) ----
    if (doLo) {
      v4f sc[4] = {};
#pragma unroll
      for (int ni = 0; ni < 4; ni++) {
        sc[ni] = MFMA16(kf0[ni], bq[0][0], sc[ni]);
        sc[ni] = MFMA16(kf1[ni], bq[0][1], sc[ni]);
      }
      if (cI == qlo) {
#pragma unroll
        for (int ni = 0; ni < 4; ni++) {
          const int key = kc + ni * 16 + quad * 4;
#pragma unroll
          for (int r = 0; r < 4; r++)
            if (key + r > qrow_lo) sc[ni][r] = -1e30f;
        }
      }
#pragma unroll
      for (int ni = 0; ni < 4; ni++) {
        const float p0 = exp2f(sc[ni][0]), p1 = exp2f(sc[ni][1]);
        const float p2 = exp2f(sc[ni][2]), p3 = exp2f(sc[ni][3]);
        uint2 pk;
        pk.x = __builtin_amdgcn_perm(__float_as_uint(p1), __float_as_uint(p0), 0x07060302u);
        pk.y = __builtin_amdgcn_perm(__float_as_uint(p3), __float_as_uint(p2), 0x07060302u);
        *(uint2*)&Ps[w][l15 * LP + ni * 16 + quad * 4] = pk;
      }
    }

    // ---- O += P @ V, l += P @ 1; V fragments shared across tiles ----
#pragma unroll
    for (int ki = 0; ki < 2; ki++) {
      v8bf pahi = *(const v8bf*)&Ps[w][(16 + l15) * LP + ki * 32 + quad * 8];
      lacc[1] = MFMA16(pahi, ones, lacc[1]);
      v8bf palo;
      if (doLo) {
        palo = *(const v8bf*)&Ps[w][l15 * LP + ki * 32 + quad * 8];
        lacc[0] = MFMA16(palo, ones, lacc[0]);
      }
#pragma unroll
      for (int ni = 0; ni < 4; ni++) {
        v8bf vb = *(const v8bf*)&Vs[(ni * 16 + l15) * LP + ki * 32 + quad * 8];
        o[1][ni] = MFMA16(pahi, vb, o[1][ni]);
        if (doLo) o[0][ni] = MFMA16(palo, vb, o[0][ni]);
      }
    }
  }

  // epilogue: normalize and store both tiles (C-layout rows = quad*4+r)
#pragma unroll
  for (int tl = 0; tl < 2; tl++) {
    const int q0 = tl ? q0hi : q0lo;
    const int row_base = q0 + w * 16 + quad * 4;
    float invl[4];
#pragma unroll
    for (int r = 0; r < 4; r++) invl[r] = 1.0f / lacc[tl][r];
#pragma unroll
    for (int ni = 0; ni < 4; ni++)
#pragma unroll
      for (int r = 0; r < 4; r++) {
        const int tr = b_ * SEQ + row_base + r;
        ATTN[(size_t)tr * HDIM + h * HS + ni * 16 + l15] = f2bf(o[tl][ni][r] * invl[r]);
      }
  }
}

// ---------------- GEMM2: out(4096x1024) = ATTN @ WOT^T, fp32 out ----------------
// 128x64 tiles -> 512 blocks (2/CU) for latency hiding.
__global__ __launch_bounds__(256) void gemm_out_kernel(
    const unsigned short* __restrict__ Ab, const unsigned short* __restrict__ Wt,
    float* __restrict__ out) {
  __shared__ unsigned short As[128 * 32];
  __shared__ unsigned short Bs[64 * 32];
  const int m0 = blockIdx.x * 128;
  const int n0 = blockIdx.y * 64;
  const int t = threadIdx.x;
  const int lane = t & 63, w = t >> 6;
  const int wm = w * 32;
  const int quad = lane >> 4, l15 = lane & 15;

  v4f acc[2][4] = {};

  const int rowA = t >> 2;
  const int colA = (t & 3) * 8;
  const unsigned short* gA = Ab + (size_t)(m0 + rowA) * HDIM + colA;
  const unsigned short* gB = Wt + (size_t)(n0 + rowA) * HDIM + colA;
  unsigned short* lA = &As[t * 8];
  unsigned short* lB = &Bs[t * 8];   // only first 64 rows' worth used

  for (int k0 = 0; k0 < HDIM; k0 += 32) {
    __syncthreads();
    async16(gA + k0, lA);
    async16(gA + 64 * HDIM + k0, lA + 64 * 32);
    if (rowA < 64) async16(gB + k0, lB);
    __syncthreads();
    v8bf a[2], b[4];
#pragma unroll
    for (int i = 0; i < 2; i++)
      a[i] = *(const v8bf*)&As[(wm + i * 16 + l15) * 32 + quad * 8];
#pragma unroll
    for (int j = 0; j < 4; j++)
      b[j] = *(const v8bf*)&Bs[(j * 16 + l15) * 32 + quad * 8];
#pragma unroll
    for (int i = 0; i < 2; i++)
#pragma unroll
      for (int j = 0; j < 4; j++)
        acc[i][j] = MFMA16(a[i], b[j], acc[i][j]);
  }

#pragma unroll
  for (int i = 0; i < 2; i++) {
#pragma unroll
    for (int j = 0; j < 4; j++) {
#pragma unroll
      for (int r = 0; r < 4; r++) {
        const int tr = m0 + wm + i * 16 + quad * 4 + r;
        const int c = n0 + j * 16 + l15;
        out[(size_t)tr * HDIM + c] = acc[i][j][r];
      }
    }
  }
}

extern "C" void kernel_launch(void* const* d_in, const int* in_sizes, int n_in,
                              void* d_out, int out_size, void* d_ws, size_t ws_size,
                              hipStream_t stream) {
  (void)in_sizes; (void)n_in; (void)out_size; (void)ws_size;
  const float* x    = (const float*)d_in[0];
  const float* pos  = (const float*)d_in[1];
  const float* Wqkv = (const float*)d_in[2];
  const float* Wout = (const float*)d_in[3];
  float* out = (float*)d_out;

  char* ws = (char*)d_ws;
  unsigned short* XP   = (unsigned short*)(ws);
  unsigned short* X    = (unsigned short*)(ws + ((size_t)8  << 20));
  unsigned short* WQT  = (unsigned short*)(ws + ((size_t)16 << 20));
  unsigned short* WOT  = (unsigned short*)(ws + ((size_t)22 << 20));
  unsigned short* Qb   = (unsigned short*)(ws + ((size_t)24 << 20));
  unsigned short* Kb   = (unsigned short*)(ws + ((size_t)32 << 20));
  unsigned short* VTb  = (unsigned short*)(ws + ((size_t)40 << 20));
  unsigned short* ATTN = (unsigned short*)(ws + ((size_t)48 << 20));

  prep_all_kernel<<<8192, 256, 0, stream>>>(x, pos, Wqkv, Wout, X, XP, WQT, WOT);

  dim3 g1(TOKENS / 128, 3 * HDIM / 128);
  gemm_qkv_kernel<<<g1, 256, 0, stream>>>(XP, X, WQT, Qb, Kb, VTb);

  dim3 g2(2 * NHEADS, 16);
  attn_pair_kernel<<<g2, 256, 0, stream>>>(Qb, Kb, VTb, ATTN);

  dim3 g3(TOKENS / 128, HDIM / 64);
  gemm_out_kernel<<<g3, 256, 0, stream>>>(ATTN, WOT, out);
}